// Round 5
// baseline (469.725 us; speedup 1.0000x reference)
//
#include <hip/hip_runtime.h>
#include <hip/hip_bf16.h>
#include <stdint.h>

// Problem constants (fixed shapes)
#define BB 16
#define HH 32
#define WW 64
#define CC 768
#define W2C 33                   // WW/2+1
#define ROWW (2*CC)              // 1536 = NB*2*BS, spectral row layout (nb, interleaved re/im)

typedef __bf16 bf16x8 __attribute__((ext_vector_type(8)));
typedef float f32x4 __attribute__((ext_vector_type(4)));

__device__ __forceinline__ unsigned short f2bf(float f) {
  __hip_bfloat16 h = __float2bfloat16(f);
  return __builtin_bit_cast(unsigned short, h);
}
__device__ __forceinline__ float bf2f(unsigned short u) {
  union { unsigned int i; float f; } x;
  x.i = ((unsigned int)u) << 16;
  return x.f;
}

// async global->LDS, 16B per lane (GEMM staging)
__device__ __forceinline__ void g2l16(const void* g, void* l) {
  __builtin_amdgcn_global_load_lds((const __attribute__((address_space(1))) unsigned int*)g,
                                   (__attribute__((address_space(3))) unsigned int*)l,
                                   16, 0, 0);
}

#define WAITVM(n) asm volatile("s_waitcnt vmcnt(" #n ")" ::: "memory")
#define MEMFENCE() asm volatile("" ::: "memory")

// compile-time bit reversal (folds after full unroll)
__device__ __host__ constexpr int brevc(int x, int bits) {
  int r = 0;
  for (int i = 0; i < bits; ++i) r |= ((x >> i) & 1) << (bits - 1 - i);
  return r;
}

// ---------------- compile-time twiddle table (W64^k = (cos, -sin)) ----------------
constexpr double TPI = 6.283185307179586476925286766559;
constexpr double tsin_(double x) {
  double t = x, s = x, x2 = x * x;
  for (int i = 1; i < 14; ++i) { t *= -x2 / (double)((2 * i) * (2 * i + 1)); s += t; }
  return s;
}
constexpr double tcos_(double x) {
  double t = 1.0, s = 1.0, x2 = x * x;
  for (int i = 1; i < 14; ++i) { t *= -x2 / (double)((2 * i - 1) * (2 * i)); s += t; }
  return s;
}
struct Tw64 { float c[64]; float s[64]; };
constexpr Tw64 mk_tw() {
  Tw64 r{};
  for (int k = 0; k < 64; ++k) {
    int q = k >> 4, m = k & 15;
    double a = (TPI / 64.0) * m;       // in [0, pi/2)
    double cq = tcos_(a), sq = tsin_(a);
    double c, s;
    if (q == 0)      { c =  cq; s =  sq; }
    else if (q == 1) { c = -sq; s =  cq; }
    else if (q == 2) { c = -cq; s = -sq; }
    else             { c =  sq; s = -cq; }
    r.c[k] = (float)c;
    r.s[k] = (float)(-s);              // store -sin
  }
  return r;
}
constexpr Tw64 TW = mk_tw();

// ---------------- radix-2 DIF FFT in registers (32-point), constant twiddles --------
template<int N, bool INV>
__device__ __forceinline__ void fft_reg(float2 (&v)[N]) {
  constexpr int LOG2N = (N == 64) ? 6 : 5;
#pragma unroll
  for (int s = 0; s < LOG2N; ++s) {
    const int len = N >> s;
    const int half = len >> 1;
    const int tstep = 64 / len;
#pragma unroll
    for (int i = 0; i < N; i += len) {
#pragma unroll
      for (int j = 0; j < half; ++j) {
        float2 u = v[i + j];
        float2 t = v[i + j + half];
        float sr = u.x + t.x, si = u.y + t.y;
        float dr = u.x - t.x, di = u.y - t.y;
        float wr = TW.c[j * tstep];
        float wi = INV ? -TW.s[j * tstep] : TW.s[j * tstep];
        v[i + j] = make_float2(sr, si);
        v[i + j + half] = make_float2(dr * wr - di * wi, dr * wi + di * wr);
      }
    }
  }
}

// ---------------- forward pass A: rfft64 along W, LDS-staged wide loads ----------------
__global__ __launch_bounds__(128) void fft_fwd_w(const float* __restrict__ x,
                                                 ushort2* __restrict__ yw,
                                                 unsigned short* __restrict__ xb) {
  __shared__ __align__(16) float xs[32][128];
  const int t = threadIdx.x;
  const int bh = blockIdx.x;
  const int c0 = blockIdx.y * 128;
  const float* xrow = x + (size_t)bh * (WW * CC) + c0;
  unsigned short* xbrow = xb + (size_t)bh * (WW * CC) + c0;
  const int rg = t >> 5;        // row group 0..3
  const int lc = (t & 31) * 4;  // float col within 128
  float2 v[32];
#pragma unroll
  for (int half = 0; half < 2; ++half) {
    if (half) __syncthreads();
    float4 f[8];
#pragma unroll
    for (int it = 0; it < 8; ++it)
      f[it] = *(const float4*)(xrow + (size_t)(half * 32 + it * 4 + rg) * CC + lc);
#pragma unroll
    for (int it = 0; it < 8; ++it) {
      *(float4*)&xs[it * 4 + rg][lc] = f[it];
      *(ushort4*)(xbrow + (size_t)(half * 32 + it * 4 + rg) * CC + lc) =
          make_ushort4(f2bf(f[it].x), f2bf(f[it].y), f2bf(f[it].z), f2bf(f[it].w));
    }
    __syncthreads();
#pragma unroll
    for (int n = 0; n < 16; ++n)
      v[half * 16 + n] = make_float2(xs[2 * n][t], xs[2 * n + 1][t]);
  }
  fft_reg<32, false>(v);
  ushort2* yp = yw + (size_t)bh * (W2C * CC) + c0 + t;
  {
    float2 Z0 = v[0];
    yp[0] = make_ushort2(f2bf(Z0.x + Z0.y), f2bf(0.f));
    yp[(size_t)32 * CC] = make_ushort2(f2bf(Z0.x - Z0.y), f2bf(0.f));
  }
#pragma unroll
  for (int k = 1; k < 32; ++k) {
    float2 Zk = v[brevc(k, 5)];
    float2 Zm = v[brevc(32 - k, 5)];
    float Er = 0.5f * (Zk.x + Zm.x), Ei = 0.5f * (Zk.y - Zm.y);
    float Odr = 0.5f * (Zk.y + Zm.y), Odi = -0.5f * (Zk.x - Zm.x);
    float wx = TW.c[k], wy = TW.s[k];
    float Xr = Er + wx * Odr - wy * Odi;
    float Xi = Ei + wx * Odi + wy * Odr;
    yp[(size_t)k * CC] = make_ushort2(f2bf(Xr), f2bf(Xi));
  }
}

// ---------------- forward pass B: complex DFT along H, scale, interleaved GEMM layout --
// xf row layout per nb-block: col p = 2*cc + (im?1:0)  ->  re/im stored as one ushort2.
__global__ __launch_bounds__(256) void fft_fwd_h(const ushort2* __restrict__ yw,
                                                 unsigned short* __restrict__ xf) {
  const int bk = blockIdx.x;
  const int b = bk / W2C, kw = bk - b * W2C;
  const int c = blockIdx.y * 256 + threadIdx.x;
  const ushort2* yp = yw + ((size_t)b * HH * W2C + kw) * CC + c;
  float2 v[32];
#pragma unroll
  for (int h = 0; h < 32; ++h) {
    ushort2 u = yp[(size_t)h * (W2C * CC)];
    v[h] = make_float2(bf2f(u.x), bf2f(u.y));
  }
  fft_reg<32, false>(v);
  const int nb = c / 192, cc = c - nb * 192;
  ushort2* xp = (ushort2*)(xf + (size_t)nb * 384 + 2 * cc);
  const float s = 0.022097086912079608f; // 1/sqrt(2048)
#pragma unroll
  for (int kh = 0; kh < 32; ++kh) {
    float2 z = v[brevc(kh, 5)];
    size_t m = ((size_t)b * HH + kh) * W2C + kw;
    xp[m * (ROWW / 2)] = make_ushort2(f2bf(z.x * s), f2bf(z.y * s));
  }
}

// ---------------- inverse pass A: complex inverse DFT along H (interleaved reads) -----
__global__ __launch_bounds__(256) void fft_inv_h(const unsigned short* __restrict__ r2,
                                                 ushort2* __restrict__ g) {
  const int bk = blockIdx.x;
  const int b = bk / W2C, kw = bk - b * W2C;
  const int c = blockIdx.y * 256 + threadIdx.x;
  const int nb = c / 192, cc = c - nb * 192;
  const ushort2* rp = (const ushort2*)(r2 + (size_t)nb * 384 + 2 * cc);
  float2 v[32];
#pragma unroll
  for (int kh = 0; kh < 32; ++kh) {
    size_t m = ((size_t)b * HH + kh) * W2C + kw;
    ushort2 u = rp[m * (ROWW / 2)];
    v[kh] = make_float2(bf2f(u.x), bf2f(u.y));
  }
  fft_reg<32, true>(v);
  ushort2* gp = g + ((size_t)b * HH * W2C + kw) * CC + c;
#pragma unroll
  for (int h = 0; h < 32; ++h) {
    float2 z = v[brevc(h, 5)];
    gp[(size_t)h * (W2C * CC)] = make_ushort2(f2bf(z.x), f2bf(z.y));
  }
}

// ---------------- inverse pass B: irfft64 along W + bias, LDS-staged wide stores -------
__global__ __launch_bounds__(128) void fft_inv_w(const ushort2* __restrict__ g,
                                                 const unsigned short* __restrict__ biasb,
                                                 float* __restrict__ out) {
  __shared__ __align__(16) float ys[32][128];
  const int t = threadIdx.x;
  const int bh = blockIdx.x;
  const int c0 = blockIdx.y * 128;
  const ushort2* gp = g + (size_t)bh * (W2C * CC) + c0 + t;
  float2 v[32];
  {
    float X0 = bf2f(gp[0].x);
    float X32 = bf2f(gp[(size_t)32 * CC].x);
    v[0] = make_float2(0.5f * (X0 + X32), 0.5f * (X0 - X32));
  }
#pragma unroll
  for (int k = 1; k < 32; ++k) {
    ushort2 uk = gp[(size_t)k * CC];
    ushort2 um = gp[(size_t)(32 - k) * CC];
    float2 Xk = make_float2(bf2f(uk.x), bf2f(uk.y));
    float2 Xm = make_float2(bf2f(um.x), bf2f(um.y));
    float Ar = 0.5f * (Xk.x + Xm.x), Ai = 0.5f * (Xk.y - Xm.y);
    float Dr = 0.5f * (Xk.x - Xm.x), Di = 0.5f * (Xk.y + Xm.y);
    float wx = TW.c[k], wy = TW.s[k];
    float Br = wx * Dr + wy * Di;
    float Bi = wx * Di - wy * Dr;
    v[k] = make_float2(Ar - Bi, Ai + Br);
  }
  fft_reg<32, true>(v);
  const float s2 = 0.04419417382415922f; // 2/sqrt(2048)
  float* orow = out + (size_t)bh * (WW * CC) + c0;
  const unsigned short* brow = biasb + (size_t)bh * (WW * CC) + c0;
  const int rg = t >> 5;
  const int lc = (t & 31) * 4;
#pragma unroll
  for (int half = 0; half < 2; ++half) {
    if (half) __syncthreads();
    ushort4 b4[8];
#pragma unroll
    for (int it = 0; it < 8; ++it)
      b4[it] = *(const ushort4*)(brow + (size_t)(half * 32 + it * 4 + rg) * CC + lc);
#pragma unroll
    for (int n = 0; n < 16; ++n) {
      float2 z = v[brevc(half * 16 + n, 5)];
      ys[2 * n][t] = z.x * s2;
      ys[2 * n + 1][t] = z.y * s2;
    }
    __syncthreads();
#pragma unroll
    for (int it = 0; it < 8; ++it) {
      const int w = half * 32 + it * 4 + rg;
      float4 f = *(const float4*)&ys[it * 4 + rg][lc];
      f.x += bf2f(b4[it].x); f.y += bf2f(b4[it].y);
      f.z += bf2f(b4[it].z); f.w += bf2f(b4[it].w);
      *(float4*)(orow + (size_t)w * CC + lc) = f;
    }
  }
}

// ---------------- bf16 MFMA GEMM: min-2-phase (T3) -------------------------------------
// Double-buffered LDS; next K-tile's global_load_lds issued BEFORE computing current;
// one vmcnt(0)+barrier per K-step. Safety: ds_reads of buf[cur] are lgkm-drained before
// the MFMAs that precede the barrier; all waves' stages drained at the same barrier ->
// restaging buf[cur] next iteration is race-free. XOR k-chunk swizzle unchanged.
template<bool RELU, bool OBF>
__global__ __launch_bounds__(256) void gemm_bt(
    const unsigned short* __restrict__ A, int lda, int aZ,
    const unsigned short* __restrict__ Bw, int K, int bZ,
    const float* __restrict__ bias, int biasZ,
    void* __restrict__ outp, int ldo, int oZ) {
  __shared__ __align__(16) unsigned short As[2][128 * 32];
  __shared__ __align__(16) unsigned short Bs[2][128 * 32];
  const int t = threadIdx.x;
  const int z = blockIdx.z;
  const size_t m0 = (size_t)blockIdx.x * 128;
  const int n0 = blockIdx.y * 128;
  const unsigned short* Ap = A + m0 * lda + (size_t)z * aZ;
  const unsigned short* Bp = Bw + (size_t)n0 * K + (size_t)z * bZ;
  const int lane = t & 63, wave = t >> 6;
  const int lr = lane & 15, quad = lane >> 4;
  const int wm = (wave >> 1) * 64, wn = (wave & 1) * 64;
  const int row = t >> 2;                     // 0..63
  const int sl = t & 3;                       // 16B slot within row
  const int kb = (sl ^ ((row >> 1) & 3)) * 8; // swizzled global k-chunk
  const int swzf = (lr >> 1) & 3;             // fragment-read swizzle
  const int NT = K >> 5;
  f32x4 acc[4][4] = {};

#define STG(k0_, s_) do { \
    const unsigned short* ga_ = Ap + (size_t)row * lda + ((k0_) + kb); \
    g2l16(ga_, &As[s_][row * 32 + sl * 8]); \
    g2l16(ga_ + (size_t)64 * lda, &As[s_][(row + 64) * 32 + sl * 8]); \
    const unsigned short* gb_ = Bp + (size_t)row * K + ((k0_) + kb); \
    g2l16(gb_, &Bs[s_][row * 32 + sl * 8]); \
    g2l16(gb_ + (size_t)64 * K, &Bs[s_][(row + 64) * 32 + sl * 8]); \
  } while (0)

  STG(0, 0);
  WAITVM(0);
  MEMFENCE(); __builtin_amdgcn_s_barrier(); MEMFENCE();
  int cur = 0;
  for (int tt = 0; tt < NT; ++tt) {
    if (tt + 1 < NT) STG((tt + 1) * 32, cur ^ 1);
    bf16x8 af[4], bfr[4];
#pragma unroll
    for (int mi = 0; mi < 4; ++mi)
      af[mi] = *(const bf16x8*)&As[cur][(wm + mi * 16 + lr) * 32 + ((quad ^ swzf) * 8)];
#pragma unroll
    for (int ni = 0; ni < 4; ++ni)
      bfr[ni] = *(const bf16x8*)&Bs[cur][(wn + ni * 16 + lr) * 32 + ((quad ^ swzf) * 8)];
    __builtin_amdgcn_s_setprio(1);
#pragma unroll
    for (int mi = 0; mi < 4; ++mi)
#pragma unroll
      for (int ni = 0; ni < 4; ++ni)
        acc[mi][ni] = __builtin_amdgcn_mfma_f32_16x16x32_bf16(af[mi], bfr[ni], acc[mi][ni], 0, 0, 0);
    __builtin_amdgcn_s_setprio(0);
    if (tt + 1 < NT) {
      WAITVM(0);
      MEMFENCE(); __builtin_amdgcn_s_barrier(); MEMFENCE();
      cur ^= 1;
    }
  }
#undef STG

#pragma unroll
  for (int mi = 0; mi < 4; ++mi) {
    const size_t mrow = m0 + wm + mi * 16 + quad * 4;
#pragma unroll
    for (int ni = 0; ni < 4; ++ni) {
      const int ncol = n0 + wn + ni * 16 + lr;
      const float bv = bias[z * biasZ + ncol];
#pragma unroll
      for (int r = 0; r < 4; ++r) {
        float vv = acc[mi][ni][r] + bv;
        if (RELU) vv = fmaxf(vv, 0.f);
        const size_t off = (mrow + r) * (size_t)ldo + (size_t)z * oZ + ncol;
        if (OBF) ((unsigned short*)outp)[off] = f2bf(vv);
        else ((float*)outp)[off] = vv;
      }
    }
  }
}

// ---------------- prep kernels ----------------
__global__ __launch_bounds__(256) void cvt_bf16(const float* __restrict__ in,
                                                unsigned short* __restrict__ outp) {
  const size_t i = ((size_t)blockIdx.x * 256 + threadIdx.x) * 4;
  float4 v = *(const float4*)(in + i);
  ushort4 o = make_ushort4(f2bf(v.x), f2bf(v.y), f2bf(v.z), f2bf(v.w));
  *(ushort4*)(outp + i) = o;
}

// Combined layer-1 weights, interleaved layout: col/row index p = 2*idx + (im?1:0)
__global__ __launch_bounds__(256) void build_w1(const float* __restrict__ w1,
                                                const float* __restrict__ b1,
                                                unsigned short* __restrict__ w1t,
                                                float* __restrict__ bias1) {
  const int idx = blockIdx.x * 256 + threadIdx.x;
  const int nb = idx / (384 * 384);
  const int rem = idx - nb * (384 * 384);
  const int n = rem / 384, k = rem - (rem / 384) * 384;
  const bool khi = k >= 192, nhi = n >= 192;
  const int kk = khi ? k - 192 : k, nn = nhi ? n - 192 : n;
  float val;
  if (!khi && !nhi)      val =  w1[((0 * 4 + nb) * 192 + kk) * 192 + nn];
  else if (khi && !nhi)  val = -w1[((1 * 4 + nb) * 192 + kk) * 192 + nn];
  else if (!khi && nhi)  val =  w1[((1 * 4 + nb) * 192 + kk) * 192 + nn];
  else                   val =  w1[((0 * 4 + nb) * 192 + kk) * 192 + nn];
  const int k2 = 2 * kk + (khi ? 1 : 0);
  const int n2 = 2 * nn + (nhi ? 1 : 0);
  w1t[((size_t)nb * 384 + n2) * 384 + k2] = f2bf(val);
  if (k == 0)
    bias1[nb * 384 + n2] = nhi ? b1[(1 * 4 + nb) * 192 + nn] : b1[(0 * 4 + nb) * 192 + nn];
}

// Combined layer-2 weights (folds the in-place r2->i2 dependency), interleaved layout.
__global__ __launch_bounds__(256) void build_w2(const float* __restrict__ w2,
                                                const float* __restrict__ b2,
                                                unsigned short* __restrict__ w2t,
                                                float* __restrict__ bias2) {
  const int idx = blockIdx.x * 256 + threadIdx.x;
  const int nb = idx / (384 * 384);
  const int rem = idx - nb * (384 * 384);
  const int n = rem / 384, k = rem - (rem / 384) * 384;
  const bool khi = k >= 192, nhi = n >= 192;
  const int kk = khi ? k - 192 : k, nn = nhi ? n - 192 : n;
  float val;
  if (!khi && !nhi) {
    val = w2[((0 * 4 + nb) * 192 + kk) * 192 + nn];
  } else if (khi && !nhi) {
    val = -w2[((1 * 4 + nb) * 192 + kk) * 192 + nn];
  } else if (!khi && nhi) {
    float s = 0.f;
    for (int d = 0; d < 192; ++d)
      s += w2[((0 * 4 + nb) * 192 + kk) * 192 + d] * w2[((1 * 4 + nb) * 192 + d) * 192 + nn];
    val = s;
  } else {
    float s = 0.f;
    for (int d = 0; d < 192; ++d)
      s += w2[((1 * 4 + nb) * 192 + kk) * 192 + d] * w2[((1 * 4 + nb) * 192 + d) * 192 + nn];
    val = w2[((0 * 4 + nb) * 192 + kk) * 192 + nn] - s;
  }
  const int k2 = 2 * kk + (khi ? 1 : 0);
  const int n2 = 2 * nn + (nhi ? 1 : 0);
  w2t[((size_t)nb * 384 + n2) * 384 + k2] = f2bf(val);
  if (k == 0) {
    float bv;
    if (!nhi) {
      bv = b2[(0 * 4 + nb) * 192 + nn];
    } else {
      float s = 0.f;
      for (int d = 0; d < 192; ++d)
        s += b2[(0 * 4 + nb) * 192 + d] * w2[((1 * 4 + nb) * 192 + d) * 192 + nn];
      bv = b2[(1 * 4 + nb) * 192 + nn] + s;
    }
    bias2[nb * 384 + n2] = bv;
  }
}

// ---------------- launcher ----------------
extern "C" void kernel_launch(void* const* d_in, const int* in_sizes, int n_in,
                              void* d_out, int out_size, void* d_ws, size_t ws_size,
                              hipStream_t stream) {
  (void)in_sizes; (void)n_in; (void)out_size; (void)ws_size;
  const float* x  = (const float*)d_in[0];
  const float* w1 = (const float*)d_in[1];
  const float* b1 = (const float*)d_in[2];
  const float* w2 = (const float*)d_in[3];
  const float* b2 = (const float*)d_in[4];
  const float* bw = (const float*)d_in[5];
  const float* bb = (const float*)d_in[6];
  float* out = (float*)d_out;

  // workspace (aliased lifetimes):
  //   buf1: Yw -> R1I1 -> G
  //   buf2: x_bf16 -> xf -> R2I2
  //   buf3: bias_bf16 (written early, read at the very end)
  char* p = (char*)d_ws;
  unsigned short* buf1 = (unsigned short*)p; p += 51904512;
  unsigned short* buf2 = (unsigned short*)p; p += 51904512;
  unsigned short* buf3 = (unsigned short*)p; p += 51904512;
  unsigned short* bwb  = (unsigned short*)p; p += 1179648;
  unsigned short* w1t  = (unsigned short*)p; p += 1179648;
  unsigned short* w2t  = (unsigned short*)p; p += 1179648;
  float* bias1 = (float*)p; p += 6144;
  float* bias2 = (float*)p; p += 6144;

  // prep (small)
  cvt_bf16<<<589824 / 1024, 256, 0, stream>>>(bw, bwb);
  build_w1<<<589824 / 256, 256, 0, stream>>>(w1, b1, w1t, bias1);
  build_w2<<<589824 / 256, 256, 0, stream>>>(w2, b2, w2t, bias2);
  // forward FFT pass A (emits Yw into buf1 and x_bf16 into buf2)
  fft_fwd_w<<<dim3(BB * HH, 6), 128, 0, stream>>>(x, (ushort2*)buf1, buf2);
  // bias path GEMM while x_bf16 is L3-hot (M=32768, N=768, K=768) -> bf16 into buf3
  gemm_bt<false, true><<<dim3(256, 6, 1), 256, 0, stream>>>(
      buf2, 768, 0, bwb, 768, 0, bb, 0, buf3, 768, 0);
  // forward FFT pass B: Yw (buf1) -> xf (buf2; x_bf16 is dead now)
  fft_fwd_h<<<dim3(BB * W2C, 3), 256, 0, stream>>>((const ushort2*)buf1, buf2);
  // spectral layer 1: xf (buf2) -> R1I1 (buf1; Yw dead)
  gemm_bt<true, true><<<dim3(132, 3, 4), 256, 0, stream>>>(
      buf2, ROWW, 384, w1t, 384, 384 * 384, bias1, 384, buf1, ROWW, 384);
  // spectral layer 2: R1I1 (buf1) -> R2I2 (buf2; xf dead)
  gemm_bt<false, true><<<dim3(132, 3, 4), 256, 0, stream>>>(
      buf1, ROWW, 384, w2t, 384, 384 * 384, bias2, 384, buf2, ROWW, 384);
  // inverse FFT: R2I2 (buf2) -> G (buf1), then irfft + bias (buf3) -> out
  fft_inv_h<<<dim3(BB * W2C, 3), 256, 0, stream>>>(buf2, (ushort2*)buf1);
  fft_inv_w<<<dim3(BB * HH, 6), 128, 0, stream>>>((const ushort2*)buf1, buf3, out);
}

// Round 6
// 438.093 us; speedup vs baseline: 1.0722x; 1.0722x over previous
//
#include <hip/hip_runtime.h>
#include <hip/hip_bf16.h>
#include <stdint.h>

// Problem constants (fixed shapes)
#define BB 16
#define HH 32
#define WW 64
#define CC 768
#define W2C 33                   // WW/2+1
#define ROWW (2*CC)              // 1536 = NB*2*BS, spectral row layout (nb, interleaved re/im)

typedef __bf16 bf16x8 __attribute__((ext_vector_type(8)));
typedef float f32x4 __attribute__((ext_vector_type(4)));

__device__ __forceinline__ unsigned short f2bf(float f) {
  __hip_bfloat16 h = __float2bfloat16(f);
  return __builtin_bit_cast(unsigned short, h);
}
__device__ __forceinline__ float bf2f(unsigned short u) {
  union { unsigned int i; float f; } x;
  x.i = ((unsigned int)u) << 16;
  return x.f;
}

// async global->LDS, 16B per lane (GEMM staging)
__device__ __forceinline__ void g2l16(const void* g, void* l) {
  __builtin_amdgcn_global_load_lds((const __attribute__((address_space(1))) unsigned int*)g,
                                   (__attribute__((address_space(3))) unsigned int*)l,
                                   16, 0, 0);
}

#define WAITVM(n) asm volatile("s_waitcnt vmcnt(" #n ")" ::: "memory")
#define LGKM0() asm volatile("s_waitcnt lgkmcnt(0)" ::: "memory")
#define MEMFENCE() asm volatile("" ::: "memory")

// compile-time bit reversal (folds after full unroll)
__device__ __host__ constexpr int brevc(int x, int bits) {
  int r = 0;
  for (int i = 0; i < bits; ++i) r |= ((x >> i) & 1) << (bits - 1 - i);
  return r;
}

// ---------------- compile-time twiddle table (W64^k = (cos, -sin)) ----------------
constexpr double TPI = 6.283185307179586476925286766559;
constexpr double tsin_(double x) {
  double t = x, s = x, x2 = x * x;
  for (int i = 1; i < 14; ++i) { t *= -x2 / (double)((2 * i) * (2 * i + 1)); s += t; }
  return s;
}
constexpr double tcos_(double x) {
  double t = 1.0, s = 1.0, x2 = x * x;
  for (int i = 1; i < 14; ++i) { t *= -x2 / (double)((2 * i - 1) * (2 * i)); s += t; }
  return s;
}
struct Tw64 { float c[64]; float s[64]; };
constexpr Tw64 mk_tw() {
  Tw64 r{};
  for (int k = 0; k < 64; ++k) {
    int q = k >> 4, m = k & 15;
    double a = (TPI / 64.0) * m;       // in [0, pi/2)
    double cq = tcos_(a), sq = tsin_(a);
    double c, s;
    if (q == 0)      { c =  cq; s =  sq; }
    else if (q == 1) { c = -sq; s =  cq; }
    else if (q == 2) { c = -cq; s = -sq; }
    else             { c =  sq; s = -cq; }
    r.c[k] = (float)c;
    r.s[k] = (float)(-s);              // store -sin
  }
  return r;
}
constexpr Tw64 TW = mk_tw();

// ---------------- radix-2 DIF FFT in registers (32-point), constant twiddles --------
template<int N, bool INV>
__device__ __forceinline__ void fft_reg(float2 (&v)[N]) {
  constexpr int LOG2N = (N == 64) ? 6 : 5;
#pragma unroll
  for (int s = 0; s < LOG2N; ++s) {
    const int len = N >> s;
    const int half = len >> 1;
    const int tstep = 64 / len;
#pragma unroll
    for (int i = 0; i < N; i += len) {
#pragma unroll
      for (int j = 0; j < half; ++j) {
        float2 u = v[i + j];
        float2 t = v[i + j + half];
        float sr = u.x + t.x, si = u.y + t.y;
        float dr = u.x - t.x, di = u.y - t.y;
        float wr = TW.c[j * tstep];
        float wi = INV ? -TW.s[j * tstep] : TW.s[j * tstep];
        v[i + j] = make_float2(sr, si);
        v[i + j + half] = make_float2(dr * wr - di * wi, dr * wi + di * wr);
      }
    }
  }
}

// ---------------- forward pass A: rfft64 along W, LDS-staged wide loads ----------------
// No xb emission anymore (bias GEMM reads x fp32 directly): writes only yw.
__global__ __launch_bounds__(128) void fft_fwd_w(const float* __restrict__ x,
                                                 ushort2* __restrict__ yw) {
  __shared__ __align__(16) float xs[32][128];
  const int t = threadIdx.x;
  const int bh = blockIdx.x;
  const int c0 = blockIdx.y * 128;
  const float* xrow = x + (size_t)bh * (WW * CC) + c0;
  const int rg = t >> 5;        // row group 0..3
  const int lc = (t & 31) * 4;  // float col within 128
  float2 v[32];
#pragma unroll
  for (int half = 0; half < 2; ++half) {
    if (half) __syncthreads();
    float4 f[8];
#pragma unroll
    for (int it = 0; it < 8; ++it)
      f[it] = *(const float4*)(xrow + (size_t)(half * 32 + it * 4 + rg) * CC + lc);
#pragma unroll
    for (int it = 0; it < 8; ++it)
      *(float4*)&xs[it * 4 + rg][lc] = f[it];
    __syncthreads();
#pragma unroll
    for (int n = 0; n < 16; ++n)
      v[half * 16 + n] = make_float2(xs[2 * n][t], xs[2 * n + 1][t]);
  }
  fft_reg<32, false>(v);
  ushort2* yp = yw + (size_t)bh * (W2C * CC) + c0 + t;
  {
    float2 Z0 = v[0];
    yp[0] = make_ushort2(f2bf(Z0.x + Z0.y), f2bf(0.f));
    yp[(size_t)32 * CC] = make_ushort2(f2bf(Z0.x - Z0.y), f2bf(0.f));
  }
#pragma unroll
  for (int k = 1; k < 32; ++k) {
    float2 Zk = v[brevc(k, 5)];
    float2 Zm = v[brevc(32 - k, 5)];
    float Er = 0.5f * (Zk.x + Zm.x), Ei = 0.5f * (Zk.y - Zm.y);
    float Odr = 0.5f * (Zk.y + Zm.y), Odi = -0.5f * (Zk.x - Zm.x);
    float wx = TW.c[k], wy = TW.s[k];
    float Xr = Er + wx * Odr - wy * Odi;
    float Xi = Ei + wx * Odi + wy * Odr;
    yp[(size_t)k * CC] = make_ushort2(f2bf(Xr), f2bf(Xi));
  }
}

// ---------------- forward pass B: complex DFT along H, scale, interleaved GEMM layout --
__global__ __launch_bounds__(256) void fft_fwd_h(const ushort2* __restrict__ yw,
                                                 unsigned short* __restrict__ xf) {
  const int bk = blockIdx.x;
  const int b = bk / W2C, kw = bk - b * W2C;
  const int c = blockIdx.y * 256 + threadIdx.x;
  const ushort2* yp = yw + ((size_t)b * HH * W2C + kw) * CC + c;
  float2 v[32];
#pragma unroll
  for (int h = 0; h < 32; ++h) {
    ushort2 u = yp[(size_t)h * (W2C * CC)];
    v[h] = make_float2(bf2f(u.x), bf2f(u.y));
  }
  fft_reg<32, false>(v);
  const int nb = c / 192, cc = c - nb * 192;
  ushort2* xp = (ushort2*)(xf + (size_t)nb * 384 + 2 * cc);
  const float s = 0.022097086912079608f; // 1/sqrt(2048)
#pragma unroll
  for (int kh = 0; kh < 32; ++kh) {
    float2 z = v[brevc(kh, 5)];
    size_t m = ((size_t)b * HH + kh) * W2C + kw;
    xp[m * (ROWW / 2)] = make_ushort2(f2bf(z.x * s), f2bf(z.y * s));
  }
}

// ---------------- inverse pass A: complex inverse DFT along H (interleaved reads) -----
__global__ __launch_bounds__(256) void fft_inv_h(const unsigned short* __restrict__ r2,
                                                 ushort2* __restrict__ g) {
  const int bk = blockIdx.x;
  const int b = bk / W2C, kw = bk - b * W2C;
  const int c = blockIdx.y * 256 + threadIdx.x;
  const int nb = c / 192, cc = c - nb * 192;
  const ushort2* rp = (const ushort2*)(r2 + (size_t)nb * 384 + 2 * cc);
  float2 v[32];
#pragma unroll
  for (int kh = 0; kh < 32; ++kh) {
    size_t m = ((size_t)b * HH + kh) * W2C + kw;
    ushort2 u = rp[m * (ROWW / 2)];
    v[kh] = make_float2(bf2f(u.x), bf2f(u.y));
  }
  fft_reg<32, true>(v);
  ushort2* gp = g + ((size_t)b * HH * W2C + kw) * CC + c;
#pragma unroll
  for (int h = 0; h < 32; ++h) {
    float2 z = v[brevc(h, 5)];
    gp[(size_t)h * (W2C * CC)] = make_ushort2(f2bf(z.x), f2bf(z.y));
  }
}

// ---------------- inverse pass B: irfft64 along W + bias, LDS-staged wide stores -------
__global__ __launch_bounds__(128) void fft_inv_w(const ushort2* __restrict__ g,
                                                 const unsigned short* __restrict__ biasb,
                                                 float* __restrict__ out) {
  __shared__ __align__(16) float ys[32][128];
  const int t = threadIdx.x;
  const int bh = blockIdx.x;
  const int c0 = blockIdx.y * 128;
  const ushort2* gp = g + (size_t)bh * (W2C * CC) + c0 + t;
  float2 v[32];
  {
    float X0 = bf2f(gp[0].x);
    float X32 = bf2f(gp[(size_t)32 * CC].x);
    v[0] = make_float2(0.5f * (X0 + X32), 0.5f * (X0 - X32));
  }
#pragma unroll
  for (int k = 1; k < 32; ++k) {
    ushort2 uk = gp[(size_t)k * CC];
    ushort2 um = gp[(size_t)(32 - k) * CC];
    float2 Xk = make_float2(bf2f(uk.x), bf2f(uk.y));
    float2 Xm = make_float2(bf2f(um.x), bf2f(um.y));
    float Ar = 0.5f * (Xk.x + Xm.x), Ai = 0.5f * (Xk.y - Xm.y);
    float Dr = 0.5f * (Xk.x - Xm.x), Di = 0.5f * (Xk.y + Xm.y);
    float wx = TW.c[k], wy = TW.s[k];
    float Br = wx * Dr + wy * Di;
    float Bi = wx * Di - wy * Dr;
    v[k] = make_float2(Ar - Bi, Ai + Br);
  }
  fft_reg<32, true>(v);
  const float s2 = 0.04419417382415922f; // 2/sqrt(2048)
  float* orow = out + (size_t)bh * (WW * CC) + c0;
  const unsigned short* brow = biasb + (size_t)bh * (WW * CC) + c0;
  const int rg = t >> 5;
  const int lc = (t & 31) * 4;
#pragma unroll
  for (int half = 0; half < 2; ++half) {
    if (half) __syncthreads();
    ushort4 b4[8];
#pragma unroll
    for (int it = 0; it < 8; ++it)
      b4[it] = *(const ushort4*)(brow + (size_t)(half * 32 + it * 4 + rg) * CC + lc);
#pragma unroll
    for (int n = 0; n < 16; ++n) {
      float2 z = v[brevc(half * 16 + n, 5)];
      ys[2 * n][t] = z.x * s2;
      ys[2 * n + 1][t] = z.y * s2;
    }
    __syncthreads();
#pragma unroll
    for (int it = 0; it < 8; ++it) {
      const int w = half * 32 + it * 4 + rg;
      float4 f = *(const float4*)&ys[it * 4 + rg][lc];
      f.x += bf2f(b4[it].x); f.y += bf2f(b4[it].y);
      f.z += bf2f(b4[it].z); f.w += bf2f(b4[it].w);
      *(float4*)(orow + (size_t)w * CC + lc) = f;
    }
  }
}

// ---------------- bf16 MFMA GEMM: min-2-phase (T3), bf16 A via global_load_lds --------
template<bool RELU, bool OBF>
__global__ __launch_bounds__(256) void gemm_bt(
    const unsigned short* __restrict__ A, int lda, int aZ,
    const unsigned short* __restrict__ Bw, int K, int bZ,
    const float* __restrict__ bias, int biasZ,
    void* __restrict__ outp, int ldo, int oZ) {
  __shared__ __align__(16) unsigned short As[2][128 * 32];
  __shared__ __align__(16) unsigned short Bs[2][128 * 32];
  const int t = threadIdx.x;
  const int z = blockIdx.z;
  const size_t m0 = (size_t)blockIdx.x * 128;
  const int n0 = blockIdx.y * 128;
  const unsigned short* Ap = A + m0 * lda + (size_t)z * aZ;
  const unsigned short* Bp = Bw + (size_t)n0 * K + (size_t)z * bZ;
  const int lane = t & 63, wave = t >> 6;
  const int lr = lane & 15, quad = lane >> 4;
  const int wm = (wave >> 1) * 64, wn = (wave & 1) * 64;
  const int row = t >> 2;                     // 0..63
  const int sl = t & 3;                       // 16B slot within row
  const int kb = (sl ^ ((row >> 1) & 3)) * 8; // swizzled global k-chunk
  const int swzf = (lr >> 1) & 3;             // fragment-read swizzle
  const int NT = K >> 5;
  f32x4 acc[4][4] = {};

#define STG(k0_, s_) do { \
    const unsigned short* ga_ = Ap + (size_t)row * lda + ((k0_) + kb); \
    g2l16(ga_, &As[s_][row * 32 + sl * 8]); \
    g2l16(ga_ + (size_t)64 * lda, &As[s_][(row + 64) * 32 + sl * 8]); \
    const unsigned short* gb_ = Bp + (size_t)row * K + ((k0_) + kb); \
    g2l16(gb_, &Bs[s_][row * 32 + sl * 8]); \
    g2l16(gb_ + (size_t)64 * K, &Bs[s_][(row + 64) * 32 + sl * 8]); \
  } while (0)

  STG(0, 0);
  WAITVM(0);
  MEMFENCE(); __builtin_amdgcn_s_barrier(); MEMFENCE();
  int cur = 0;
  for (int tt = 0; tt < NT; ++tt) {
    if (tt + 1 < NT) STG((tt + 1) * 32, cur ^ 1);
    bf16x8 af[4], bfr[4];
#pragma unroll
    for (int mi = 0; mi < 4; ++mi)
      af[mi] = *(const bf16x8*)&As[cur][(wm + mi * 16 + lr) * 32 + ((quad ^ swzf) * 8)];
#pragma unroll
    for (int ni = 0; ni < 4; ++ni)
      bfr[ni] = *(const bf16x8*)&Bs[cur][(wn + ni * 16 + lr) * 32 + ((quad ^ swzf) * 8)];
    __builtin_amdgcn_s_setprio(1);
#pragma unroll
    for (int mi = 0; mi < 4; ++mi)
#pragma unroll
      for (int ni = 0; ni < 4; ++ni)
        acc[mi][ni] = __builtin_amdgcn_mfma_f32_16x16x32_bf16(af[mi], bfr[ni], acc[mi][ni], 0, 0, 0);
    __builtin_amdgcn_s_setprio(0);
    if (tt + 1 < NT) {
      WAITVM(0);
      MEMFENCE(); __builtin_amdgcn_s_barrier(); MEMFENCE();
      cur ^= 1;
    }
  }
#undef STG

#pragma unroll
  for (int mi = 0; mi < 4; ++mi) {
    const size_t mrow = m0 + wm + mi * 16 + quad * 4;
#pragma unroll
    for (int ni = 0; ni < 4; ++ni) {
      const int ncol = n0 + wn + ni * 16 + lr;
      const float bv = bias[z * biasZ + ncol];
#pragma unroll
      for (int r = 0; r < 4; ++r) {
        float vv = acc[mi][ni][r] + bv;
        if (RELU) vv = fmaxf(vv, 0.f);
        const size_t off = (mrow + r) * (size_t)ldo + (size_t)z * oZ + ncol;
        if (OBF) ((unsigned short*)outp)[off] = f2bf(vv);
        else ((float*)outp)[off] = vv;
      }
    }
  }
}

// ---------------- bias-path GEMM: A = x in FP32, converted during reg-staging ---------
// Same 2-phase skeleton and LDS swizzle as gemm_bt; A-path: 4x float4 loads -> 16 f2bf
// -> 2x ds_write_b128 (same content layout g2l16 would have produced from x_bf16).
__global__ __launch_bounds__(256) void gemm_bias(
    const float* __restrict__ A,                  // x fp32, lda = 768
    const unsigned short* __restrict__ Bw,        // bwb bf16, K = 768 (n-major)
    const float* __restrict__ bias,               // bb
    unsigned short* __restrict__ outp) {          // bias_bf16, ldo = 768
  constexpr int K = 768, NT = 24, LDAF = 768;
  __shared__ __align__(16) unsigned short As[2][128 * 32];
  __shared__ __align__(16) unsigned short Bs[2][128 * 32];
  const int t = threadIdx.x;
  const size_t m0 = (size_t)blockIdx.x * 128;
  const int n0 = blockIdx.y * 128;
  const float* Ap = A + m0 * LDAF;
  const unsigned short* Bp = Bw + (size_t)n0 * K;
  const int lane = t & 63, wave = t >> 6;
  const int lr = lane & 15, quad = lane >> 4;
  const int wm = (wave >> 1) * 64, wn = (wave & 1) * 64;
  const int row = t >> 2, sl = t & 3;
  const int kb = (sl ^ ((row >> 1) & 3)) * 8;
  const int swzf = (lr >> 1) & 3;
  f32x4 acc[4][4] = {};
  float4 a0, a1, a2, a3;

#define LDA4(k0_) do { \
    const float* ga_ = Ap + (size_t)row * LDAF + ((k0_) + kb); \
    a0 = *(const float4*)ga_; a1 = *(const float4*)(ga_ + 4); \
    const float* gc_ = ga_ + (size_t)64 * LDAF; \
    a2 = *(const float4*)gc_; a3 = *(const float4*)(gc_ + 4); \
  } while (0)
#define STB(k0_, s_) do { \
    const unsigned short* gb_ = Bp + (size_t)row * K + ((k0_) + kb); \
    g2l16(gb_, &Bs[s_][row * 32 + sl * 8]); \
    g2l16(gb_ + (size_t)64 * K, &Bs[s_][(row + 64) * 32 + sl * 8]); \
  } while (0)
#define WRA(s_) do { \
    union { bf16x8 v; unsigned short u[8]; } p0_, p1_; \
    p0_.u[0] = f2bf(a0.x); p0_.u[1] = f2bf(a0.y); p0_.u[2] = f2bf(a0.z); p0_.u[3] = f2bf(a0.w); \
    p0_.u[4] = f2bf(a1.x); p0_.u[5] = f2bf(a1.y); p0_.u[6] = f2bf(a1.z); p0_.u[7] = f2bf(a1.w); \
    p1_.u[0] = f2bf(a2.x); p1_.u[1] = f2bf(a2.y); p1_.u[2] = f2bf(a2.z); p1_.u[3] = f2bf(a2.w); \
    p1_.u[4] = f2bf(a3.x); p1_.u[5] = f2bf(a3.y); p1_.u[6] = f2bf(a3.z); p1_.u[7] = f2bf(a3.w); \
    *(bf16x8*)&As[s_][row * 32 + sl * 8] = p0_.v; \
    *(bf16x8*)&As[s_][(row + 64) * 32 + sl * 8] = p1_.v; \
  } while (0)

  LDA4(0); STB(0, 0);
  WRA(0);                         // compiler inserts vmcnt waits for a0..a3 uses
  WAITVM(0); LGKM0();             // B staged + A ds_writes visible
  MEMFENCE(); __builtin_amdgcn_s_barrier(); MEMFENCE();
  int cur = 0;
  for (int tt = 0; tt < NT; ++tt) {
    if (tt + 1 < NT) { LDA4((tt + 1) * 32); STB((tt + 1) * 32, cur ^ 1); }
    bf16x8 af[4], bfr[4];
#pragma unroll
    for (int mi = 0; mi < 4; ++mi)
      af[mi] = *(const bf16x8*)&As[cur][(wm + mi * 16 + lr) * 32 + ((quad ^ swzf) * 8)];
#pragma unroll
    for (int ni = 0; ni < 4; ++ni)
      bfr[ni] = *(const bf16x8*)&Bs[cur][(wn + ni * 16 + lr) * 32 + ((quad ^ swzf) * 8)];
    __builtin_amdgcn_s_setprio(1);
#pragma unroll
    for (int mi = 0; mi < 4; ++mi)
#pragma unroll
      for (int ni = 0; ni < 4; ++ni)
        acc[mi][ni] = __builtin_amdgcn_mfma_f32_16x16x32_bf16(af[mi], bfr[ni], acc[mi][ni], 0, 0, 0);
    __builtin_amdgcn_s_setprio(0);
    if (tt + 1 < NT) {
      WRA(cur ^ 1);               // convert+write next A tile (other buffer: race-free)
      WAITVM(0); LGKM0();
      MEMFENCE(); __builtin_amdgcn_s_barrier(); MEMFENCE();
      cur ^= 1;
    }
  }
#undef LDA4
#undef STB
#undef WRA

#pragma unroll
  for (int mi = 0; mi < 4; ++mi) {
    const size_t mrow = m0 + wm + mi * 16 + quad * 4;
#pragma unroll
    for (int ni = 0; ni < 4; ++ni) {
      const int ncol = n0 + wn + ni * 16 + lr;
      const float bv = bias[ncol];
#pragma unroll
      for (int r = 0; r < 4; ++r)
        outp[(mrow + r) * (size_t)768 + ncol] = f2bf(acc[mi][ni][r] + bv);
    }
  }
}

// ---------------- prep kernels ----------------
__global__ __launch_bounds__(256) void cvt_bf16(const float* __restrict__ in,
                                                unsigned short* __restrict__ outp) {
  const size_t i = ((size_t)blockIdx.x * 256 + threadIdx.x) * 4;
  float4 v = *(const float4*)(in + i);
  ushort4 o = make_ushort4(f2bf(v.x), f2bf(v.y), f2bf(v.z), f2bf(v.w));
  *(ushort4*)(outp + i) = o;
}

// Combined layer-1 weights, interleaved layout: col/row index p = 2*idx + (im?1:0)
__global__ __launch_bounds__(256) void build_w1(const float* __restrict__ w1,
                                                const float* __restrict__ b1,
                                                unsigned short* __restrict__ w1t,
                                                float* __restrict__ bias1) {
  const int idx = blockIdx.x * 256 + threadIdx.x;
  const int nb = idx / (384 * 384);
  const int rem = idx - nb * (384 * 384);
  const int n = rem / 384, k = rem - (rem / 384) * 384;
  const bool khi = k >= 192, nhi = n >= 192;
  const int kk = khi ? k - 192 : k, nn = nhi ? n - 192 : n;
  float val;
  if (!khi && !nhi)      val =  w1[((0 * 4 + nb) * 192 + kk) * 192 + nn];
  else if (khi && !nhi)  val = -w1[((1 * 4 + nb) * 192 + kk) * 192 + nn];
  else if (!khi && nhi)  val =  w1[((1 * 4 + nb) * 192 + kk) * 192 + nn];
  else                   val =  w1[((0 * 4 + nb) * 192 + kk) * 192 + nn];
  const int k2 = 2 * kk + (khi ? 1 : 0);
  const int n2 = 2 * nn + (nhi ? 1 : 0);
  w1t[((size_t)nb * 384 + n2) * 384 + k2] = f2bf(val);
  if (k == 0)
    bias1[nb * 384 + n2] = nhi ? b1[(1 * 4 + nb) * 192 + nn] : b1[(0 * 4 + nb) * 192 + nn];
}

// Combined layer-2 weights (folds the in-place r2->i2 dependency), interleaved layout.
// Lane mapping swapped (lanes span n): the 192-iter quadrant loops now read the first
// operand wave-uniform (broadcast) and the second coalesced across lanes.
__global__ __launch_bounds__(256) void build_w2(const float* __restrict__ w2,
                                                const float* __restrict__ b2,
                                                unsigned short* __restrict__ w2t,
                                                float* __restrict__ bias2) {
  const int idx = blockIdx.x * 256 + threadIdx.x;
  const int nb = idx / (384 * 384);
  const int rem = idx - nb * (384 * 384);
  const int k = rem / 384, n = rem - (rem / 384) * 384;   // lanes span n
  const bool khi = k >= 192, nhi = n >= 192;
  const int kk = khi ? k - 192 : k, nn = nhi ? n - 192 : n;
  float val;
  if (!khi && !nhi) {
    val = w2[((0 * 4 + nb) * 192 + kk) * 192 + nn];
  } else if (khi && !nhi) {
    val = -w2[((1 * 4 + nb) * 192 + kk) * 192 + nn];
  } else if (!khi && nhi) {
    float s = 0.f;
    for (int d = 0; d < 192; ++d)
      s += w2[((0 * 4 + nb) * 192 + kk) * 192 + d] * w2[((1 * 4 + nb) * 192 + d) * 192 + nn];
    val = s;
  } else {
    float s = 0.f;
    for (int d = 0; d < 192; ++d)
      s += w2[((1 * 4 + nb) * 192 + kk) * 192 + d] * w2[((1 * 4 + nb) * 192 + d) * 192 + nn];
    val = w2[((0 * 4 + nb) * 192 + kk) * 192 + nn] - s;
  }
  const int k2 = 2 * kk + (khi ? 1 : 0);
  const int n2 = 2 * nn + (nhi ? 1 : 0);
  w2t[((size_t)nb * 384 + n2) * 384 + k2] = f2bf(val);
  if (k == 0) {
    float bv;
    if (!nhi) {
      bv = b2[(0 * 4 + nb) * 192 + nn];
    } else {
      float s = 0.f;
      for (int d = 0; d < 192; ++d)
        s += b2[(0 * 4 + nb) * 192 + d] * w2[((1 * 4 + nb) * 192 + d) * 192 + nn];
      bv = b2[(1 * 4 + nb) * 192 + nn] + s;
    }
    bias2[nb * 384 + n2] = bv;
  }
}

// ---------------- launcher ----------------
extern "C" void kernel_launch(void* const* d_in, const int* in_sizes, int n_in,
                              void* d_out, int out_size, void* d_ws, size_t ws_size,
                              hipStream_t stream) {
  (void)in_sizes; (void)n_in; (void)out_size; (void)ws_size;
  const float* x  = (const float*)d_in[0];
  const float* w1 = (const float*)d_in[1];
  const float* b1 = (const float*)d_in[2];
  const float* w2 = (const float*)d_in[3];
  const float* b2 = (const float*)d_in[4];
  const float* bw = (const float*)d_in[5];
  const float* bb = (const float*)d_in[6];
  float* out = (float*)d_out;

  // workspace (aliased lifetimes):
  //   buf1: Yw -> R1I1 -> G
  //   buf2: xf -> R2I2
  //   buf3: bias_bf16 (written early, read at the very end)
  char* p = (char*)d_ws;
  unsigned short* buf1 = (unsigned short*)p; p += 51904512;
  unsigned short* buf2 = (unsigned short*)p; p += 51904512;
  unsigned short* buf3 = (unsigned short*)p; p += 51904512;
  unsigned short* bwb  = (unsigned short*)p; p += 1179648;
  unsigned short* w1t  = (unsigned short*)p; p += 1179648;
  unsigned short* w2t  = (unsigned short*)p; p += 1179648;
  float* bias1 = (float*)p; p += 6144;
  float* bias2 = (float*)p; p += 6144;

  // prep (small)
  cvt_bf16<<<589824 / 1024, 256, 0, stream>>>(bw, bwb);
  build_w1<<<589824 / 256, 256, 0, stream>>>(w1, b1, w1t, bias1);
  build_w2<<<589824 / 256, 256, 0, stream>>>(w2, b2, w2t, bias2);
  // forward FFT pass A (emits Yw into buf1)
  fft_fwd_w<<<dim3(BB * HH, 6), 128, 0, stream>>>(x, (ushort2*)buf1);
  // bias path GEMM while x is L3-hot: A = x fp32 (M=32768, N=768, K=768) -> bf16 buf3
  gemm_bias<<<dim3(256, 6), 256, 0, stream>>>(x, bwb, bb, buf3);
  // forward FFT pass B: Yw (buf1) -> xf (buf2)
  fft_fwd_h<<<dim3(BB * W2C, 3), 256, 0, stream>>>((const ushort2*)buf1, buf2);
  // spectral layer 1: xf (buf2) -> R1I1 (buf1; Yw dead)
  gemm_bt<true, true><<<dim3(132, 3, 4), 256, 0, stream>>>(
      buf2, ROWW, 384, w1t, 384, 384 * 384, bias1, 384, buf1, ROWW, 384);
  // spectral layer 2: R1I1 (buf1) -> R2I2 (buf2; xf dead)
  gemm_bt<false, true><<<dim3(132, 3, 4), 256, 0, stream>>>(
      buf1, ROWW, 384, w2t, 384, 384 * 384, bias2, 384, buf2, ROWW, 384);
  // inverse FFT: R2I2 (buf2) -> G (buf1), then irfft + bias (buf3) -> out
  fft_inv_h<<<dim3(BB * W2C, 3), 256, 0, stream>>>(buf2, (ushort2*)buf1);
  fft_inv_w<<<dim3(BB * HH, 6), 128, 0, stream>>>((const ushort2*)buf1, buf3, out);
}